// Round 12
// baseline (346.429 us; speedup 1.0000x reference)
//
#include <hip/hip_runtime.h>
#include <hip/hip_bf16.h>
#include <cmath>

// Problem constants (B=2, N=1000, k=8 from reference)
#define NB 2
#define NP 1000
#define KNN 8
#define PPAIR 499500  // N*(N-1)/2

typedef __hip_bfloat16 bf16;
typedef unsigned long long u64;
typedef unsigned short ushort;
typedef unsigned int uint;
typedef __attribute__((ext_vector_type(8))) short short8;
typedef __attribute__((ext_vector_type(4))) float f32x4;

__device__ __forceinline__ float b2f(bf16 v) { return __bfloat162float(v); }
// f32 -> bf16 bits, round-to-nearest-even
__device__ __forceinline__ ushort f2b(float f) {
    uint x = __float_as_uint(f);
    return (ushort)((x + 0x7FFFu + ((x >> 16) & 1u)) >> 16);
}
// flag-aware element load from an input buffer
__device__ __forceinline__ float ldin(const void* p, int flag, int i) {
    return flag ? ((const float*)p)[i] : b2f(((const bf16*)p)[i]);
}

// Workspace layout (float offsets), all 16B-aligned
#define OFF_POS    0
#define OFF_C1W1   6000
#define OFF_C1B1   6096
#define OFF_C1W2   6112
#define OFF_C1B2   6624
#define OFF_C2W1   6656
#define OFF_C2B1   10752
#define OFF_C2W2   10816
#define OFF_C2B2   19008
#define OFF_C3W1   19136
#define OFF_C3B1   84672
#define OFF_C3W2   84928
#define OFF_C3B2   216000
#define OFF_SMW1   216512
#define OFF_SMB1   388544
#define OFF_SMW2   388800
#define OFF_SMB2   421568
#define OFF_ECW1   421696
#define OFF_ECB1   470848
#define OFF_ECW2   470976
#define OFF_ECB2   471104
#define OFF_X1     471112
#define OFF_X2     535112
#define OFF_X3     791112
#define OFF_SF     1815112
#define OFF_G      2071112
#define OFF_HI     2071368
#define OFF_HJ     2327368
#define OFF_HG     2583368
#define OFF_FLAG   2583624   // int
#define OFF_NIDX   2583632   // (unused since R27: knn<3> result stays in LDS)
#define OFF_GP     2599632   // (unused since R27: gmax partials fused away)
#define OFF_W1T    2606032   // ec3 W1T 256x256 bf16 (32768 f32)
#define OFF_W2T    2638800   // ec3 W2T 512x256 bf16 (65536 f32)
#define OFF_SMW1T  2704336   // sm W1T 256x672 bf16 (86016 f32)
#define OFF_SMW2T  2790352   // sm W2T 128x256 bf16 (16384 f32)
#define OFF_ECW1T  2806736   // hij WT 256x128 bf16 (16384 f32)
#define OFF_PL     2823120   // (unused since R16)
#define OFF_E2W1T  3079120   // ec2 W1T 64x64 bf16 (2048 f32)
#define OFF_E2W2T  3081168   // ec2 W2T 128x64 bf16 (4096 f32)
#define OFF_D2     3085264   // full d2 matrix [NB][NP][NP] f32 (2,000,000 f32)

// ---------------- dtype detection ----------------
__global__ void detect_kernel(const void* pos, int* flag) {
    __shared__ float red[256];
    const unsigned short* p = (const unsigned short*)pos;
    float m = 0.f;
    for (int t = threadIdx.x; t < 6000; t += 256) {
        unsigned int u = ((unsigned int)p[t]) << 16;
        float v = fabsf(__uint_as_float(u));
        if (!isfinite(v)) v = 1e30f;
        m = fmaxf(m, v);
    }
    red[threadIdx.x] = m;
    __syncthreads();
    for (int s = 128; s > 0; s >>= 1) {
        if (threadIdx.x < s) red[threadIdx.x] = fmaxf(red[threadIdx.x], red[threadIdx.x + s]);
        __syncthreads();
    }
    if (threadIdx.x == 0) flag[0] = (red[0] > 1e6f) ? 1 : 0;
}

// ---------------- convert inputs to f32 + build transposed bf16 weights ----------------
// R24: flattened 1-D grid (3591 working blocks) instead of 672x28=18816.
struct InPtrs { const void* p[21]; };

#define CVT_NSEG 28
__global__ void cvt_all_kernel(InPtrs in, float* ws, const int* flag,
                               ushort* w1t, ushort* w2t, ushort* smw1t,
                               ushort* smw2t, ushort* ecw1t,
                               ushort* e2w1t, ushort* e2w2t) {
    const int sizes[21] = {6000, 96, 16, 512, 32, 4096, 64, 8192, 128,
                           65536, 256, 131072, 512, 172032, 256, 32768, 128,
                           49152, 128, 128, 1};
    const int offs[21] = {OFF_POS, OFF_C1W1, OFF_C1B1, OFF_C1W2, OFF_C1B2,
                          OFF_C2W1, OFF_C2B1, OFF_C2W2, OFF_C2B2,
                          OFF_C3W1, OFF_C3B1, OFF_C3W2, OFF_C3B2,
                          OFF_SMW1, OFF_SMB1, OFF_SMW2, OFF_SMB2,
                          OFF_ECW1, OFF_ECB1, OFF_ECW2, OFF_ECB2};
    // cumulative block counts per segment (ceil(size/256)); see launch grid
    const int cum[CVT_NSEG + 1] = {0, 24, 25, 26, 28, 29, 45, 46, 78, 79, 335,
                                   336, 848, 850, 1522, 1523, 1651, 1652, 1844,
                                   1845, 1846, 1847, 2103, 2615, 3287, 3415,
                                   3543, 3559, 3591};
    int bid = blockIdx.x;
    int y = 0;
    while (y < CVT_NSEG - 1 && bid >= cum[y + 1]) ++y;   // uniform scalar scan
    int t = (bid - cum[y]) * 256 + threadIdx.x;
    int f = flag[0];
    if (y < 21) {
        if (t < sizes[y]) ws[offs[y] + t] = ldin(in.p[y], f, t);
    } else if (y == 21) {
        if (t < 65536) {            // ec3 W1 [c=256][h=256] -> [h][c]
            int h = t >> 8, c = t & 255;
            w1t[t] = f2b(ldin(in.p[9], f, c * 256 + h));
        }
    } else if (y == 22) {
        if (t < 131072) {           // ec3 W2 [h=256][o=512] -> [o][h]
            int o = t >> 8, h = t & 255;
            w2t[t] = f2b(ldin(in.p[11], f, h * 512 + o));
        }
    } else if (y == 23) {
        if (t < 172032) {           // sm W1 [c=672][h=256] -> [h][c]
            int h = t / 672, c = t - h * 672;
            smw1t[t] = f2b(ldin(in.p[13], f, c * 256 + h));
        }
    } else if (y == 24) {
        if (t < 32768) {            // sm W2 [h=256][o=128] -> [o][h]
            int o = t >> 8, h = t & 255;
            smw2t[t] = f2b(ldin(in.p[15], f, h * 128 + o));
        }
    } else if (y == 25) {
        if (t < 32768) {            // ec W1[:256] -> [o'][c]
            int op = t >> 7, c = t & 127;
            int idx = (op < 128) ? (c * 128 + op) : ((128 + c) * 128 + (op - 128));
            ecw1t[t] = f2b(ldin(in.p[17], f, idx));
        }
    } else if (y == 26) {
        if (t < 4096) {             // ec2 W1 [c=64][h=64] -> [h][c]
            int h = t >> 6, c = t & 63;
            e2w1t[t] = f2b(ldin(in.p[5], f, c * 64 + h));
        }
    } else {
        if (t < 8192) {             // ec2 W2 [h=64][o=128] -> [o][h]
            int o = t >> 6, h = t & 63;
            e2w2t[t] = f2b(ldin(in.p[7], f, h * 128 + o));
        }
    }
}

// ---------------- shared kNN helpers ----------------
__device__ __forceinline__ void ce(u64& a, u64& b) {
    u64 lo = a < b ? a : b;
    u64 hi = a < b ? b : a;
    a = lo; b = hi;
}

__device__ __forceinline__ u64 umin64(u64 a, u64 b) { return a < b ? a : b; }

__device__ __forceinline__ void ins8(u64 (&best)[KNN], u64 cand) {
    u64 cur = cand;
    #pragma unroll
    for (int r = 0; r < KNN; ++r) {
        u64 lo = best[r] < cur ? best[r] : cur;
        u64 hi = best[r] < cur ? cur : best[r];
        best[r] = lo; cur = hi;
    }
}

// sort 4 candidates asc, then bitonic-merge into sorted-asc best[8] (keep low 8)
__device__ __forceinline__ void merge4(u64 (&best)[KNN], u64 s0, u64 s1, u64 s2, u64 s3) {
    ce(s0, s1); ce(s2, s3); ce(s0, s2); ce(s1, s3); ce(s1, s2);   // sort4 asc
    best[4] = umin64(best[4], s3);
    best[5] = umin64(best[5], s2);
    best[6] = umin64(best[6], s1);
    best[7] = umin64(best[7], s0);
    ce(best[0], best[4]); ce(best[1], best[5]); ce(best[2], best[6]); ce(best[3], best[7]);
    ce(best[0], best[2]); ce(best[1], best[3]); ce(best[4], best[6]); ce(best[5], best[7]);
    ce(best[0], best[1]); ce(best[2], best[3]); ce(best[4], best[5]); ce(best[6], best[7]);
}

// R26: wave-level top-8 select for query q from its d2 row (knn_sel body, relocated)
__device__ __forceinline__ void wave_sel8(const float* __restrict__ row, int lane,
                                          u64 (&best)[KNN]) {
    #pragma unroll
    for (int r = 0; r < KNN; ++r) best[r] = ~0ull;
    #pragma unroll
    for (int t = 0; t < 4; ++t) {
        int j = t * 256 + lane * 4;
        if (j < NP) {   // NP%4==0 so j<NP implies j+3<NP
            float4 v = *(const float4*)(row + j);
            merge4(best,
                   (((u64)__float_as_uint(v.x)) << 32) | (unsigned)(j + 0),
                   (((u64)__float_as_uint(v.y)) << 32) | (unsigned)(j + 1),
                   (((u64)__float_as_uint(v.z)) << 32) | (unsigned)(j + 2),
                   (((u64)__float_as_uint(v.w)) << 32) | (unsigned)(j + 3));
        }
    }
    #pragma unroll
    for (int m = 1; m < 64; m <<= 1) {
        u64 other[KNN];
        #pragma unroll
        for (int r = 0; r < KNN; ++r)
            other[r] = __shfl_xor((unsigned long long)best[r], m, 64);
        u64 v[KNN];
        #pragma unroll
        for (int r = 0; r < KNN; ++r)
            v[r] = umin64(best[r], other[KNN - 1 - r]);
        ce(v[0], v[4]); ce(v[1], v[5]); ce(v[2], v[6]); ce(v[3], v[7]);
        ce(v[0], v[2]); ce(v[1], v[3]); ce(v[4], v[6]); ce(v[5], v[7]);
        ce(v[0], v[1]); ce(v[2], v[3]); ce(v[4], v[5]); ce(v[6], v[7]);
        #pragma unroll
        for (int r = 0; r < KNN; ++r) best[r] = v[r];
    }
}

// ---------------- R27: fused kNN(C=3) + EdgeConv-1 ----------------
// Phase 1: R7-proven knn_fused<3> body; top-8 kept in LDS nbl (order irrelevant:
// EdgeConv max-aggregates over neighbors). Phase 2: R25-proven wave-per-point ec1,
// looped twice (8 points/block, 4 waves). Removes ec1 launch + nidx round-trip.
__global__ __launch_bounds__(256) void knn_ec1_kernel(
        const float* __restrict__ x,
        const float* __restrict__ w1, const float* __restrict__ b1,
        const float* __restrict__ w2, const float* __restrict__ b2,
        float* __restrict__ y) {
    constexpr int C = 3, CP = 4, PSTR = 8;
    __shared__ float Qs[8 * PSTR];
    __shared__ float Ps[64 * PSTR];
    __shared__ int nbl[8][KNN];
    __shared__ float hid[4][8][17];
    int tid = threadIdx.x;
    int b = blockIdx.y;
    int i0 = blockIdx.x * 8;             // grid.x = 125 -> i0+7 <= 999 always
    int q = tid >> 5;
    int jcol = tid & 31;

    for (int idx = tid; idx < 8 * CP; idx += 256) {
        int row = idx / CP, c = idx % CP;
        int i = i0 + row;
        Qs[row * PSTR + c] = (c < C) ? x[((size_t)b * NP + i) * C + c] : 0.f;
    }

    u64 best[KNN];
    #pragma unroll
    for (int r = 0; r < KNN; ++r) best[r] = ~0ull;

    for (int jc = 0; jc < 16; ++jc) {
        int j0 = jc * 64;
        __syncthreads();
        for (int idx = tid; idx < 64 * CP; idx += 256) {
            int row = idx / CP, c = idx % CP;
            int j = j0 + row;
            Ps[row * PSTR + c] = (c < C && j < NP) ? x[((size_t)b * NP + j) * C + c] : 0.f;
        }
        __syncthreads();
        float d0 = 0.f, d1 = 0.f;
        {
            float4 qv = *(const float4*)(&Qs[q * PSTR]);
            float4 p0 = *(const float4*)(&Ps[jcol * PSTR]);
            float4 p1 = *(const float4*)(&Ps[(jcol + 32) * PSTR]);
            float t;
            t = qv.x - p0.x; d0 += t * t;  t = qv.y - p0.y; d0 += t * t;
            t = qv.z - p0.z; d0 += t * t;  t = qv.w - p0.w; d0 += t * t;
            t = qv.x - p1.x; d1 += t * t;  t = qv.y - p1.y; d1 += t * t;
            t = qv.z - p1.z; d1 += t * t;  t = qv.w - p1.w; d1 += t * t;
        }
        int ja = j0 + jcol, jb = j0 + jcol + 32;
        u64 ca = (ja < NP) ? ((((u64)__float_as_uint(d0)) << 32) | (unsigned)ja) : ~0ull;
        u64 cb = (jb < NP) ? ((((u64)__float_as_uint(d1)) << 32) | (unsigned)jb) : ~0ull;
        ins8(best, ca);
        ins8(best, cb);
    }

    #pragma unroll
    for (int m = 1; m < 32; m <<= 1) {
        u64 other[KNN];
        #pragma unroll
        for (int r = 0; r < KNN; ++r)
            other[r] = __shfl_xor((unsigned long long)best[r], m, 64);
        u64 v[KNN];
        #pragma unroll
        for (int r = 0; r < KNN; ++r)
            v[r] = best[r] < other[7 - r] ? best[r] : other[7 - r];
        ce(v[0], v[4]); ce(v[1], v[5]); ce(v[2], v[6]); ce(v[3], v[7]);
        ce(v[0], v[2]); ce(v[1], v[3]); ce(v[4], v[6]); ce(v[5], v[7]);
        ce(v[0], v[1]); ce(v[2], v[3]); ce(v[4], v[5]); ce(v[6], v[7]);
        #pragma unroll
        for (int r = 0; r < KNN; ++r) best[r] = v[r];
    }

    if (jcol == 0) {
        #pragma unroll
        for (int r = 0; r < KNN; ++r)
            nbl[q][r] = (int)(best[r] & 0xffffffffu);
    }
    __syncthreads();

    // ---- ec1 phase: wave per point, 2 points per wave ----
    int wave = tid >> 6, lane = tid & 63;
    int h = lane & 15, k2 = lane >> 4;       // k2 in 0..3
    int o = lane & 31, half = lane >> 5;
    #pragma unroll
    for (int p2 = 0; p2 < 2; ++p2) {
        int qq = p2 * 4 + wave;
        int pi = i0 + qq;
        const float* xi = x + ((size_t)b * NP + pi) * 3;
        float xi0 = xi[0], xi1 = xi[1], xi2 = xi[2];
        int nbA = nbl[qq][k2];
        int nbB = nbl[qq][k2 + 4];
        const float* xjA = x + ((size_t)b * NP + nbA) * 3;
        const float* xjB = x + ((size_t)b * NP + nbB) * 3;
        float dA0 = xjA[0] - xi0, dA1 = xjA[1] - xi1, dA2 = xjA[2] - xi2;
        float dB0 = xjB[0] - xi0, dB1 = xjB[1] - xi1, dB2 = xjB[2] - xi2;
        float wa0 = w1[h], wa1 = w1[16 + h], wa2 = w1[32 + h];
        float wb0 = w1[48 + h], wb1 = w1[64 + h], wb2 = w1[80 + h];
        float common = b1[h] + xi0 * wa0 + xi1 * wa1 + xi2 * wa2;
        hid[wave][k2][h]     = fmaxf(common + dA0 * wb0 + dA1 * wb1 + dA2 * wb2, 0.f);
        hid[wave][k2 + 4][h] = fmaxf(common + dB0 * wb0 + dB1 * wb1 + dB2 * wb2, 0.f);
        __syncthreads();
        float m = -INFINITY;
        #pragma unroll
        for (int kk = 0; kk < 4; ++kk) {
            int k = half * 4 + kk;
            float acc = 0.f;
            #pragma unroll
            for (int hh = 0; hh < 16; ++hh)
                acc += hid[wave][k][hh] * w2[hh * 32 + o];
            m = fmaxf(m, acc);
        }
        m = fmaxf(m, __shfl_xor(m, 32, 64));
        if (half == 0) y[((size_t)b * NP + pi) * 32 + o] = m + b2[o];
        __syncthreads();
    }
}

// ---------------- R16: distance-matrix kernel ----------------
template <int C>
__global__ __launch_bounds__(256) void dist_kernel(const float* __restrict__ x,
                                                   float* __restrict__ d2) {
    constexpr int CP = (C + 3) & ~3;
    constexpr int STR = CP + 4;
    __shared__ float As[32 * STR];
    __shared__ float Bs[64 * STR];
    int tid = threadIdx.x;
    int tx = tid & 31, ty = tid >> 5;
    int b = blockIdx.z;
    int i0 = blockIdx.x * 32;
    int j0 = blockIdx.y * 64;

    for (int idx = tid; idx < 32 * (CP / 4); idx += 256) {
        int row = idx / (CP / 4), c4 = idx % (CP / 4);
        int i = i0 + row;
        float4 v = make_float4(0.f, 0.f, 0.f, 0.f);
        if (i < NP) v = *(const float4*)(x + ((size_t)b * NP + i) * C + c4 * 4);
        *(float4*)(&As[row * STR + c4 * 4]) = v;
    }
    for (int idx = tid; idx < 64 * (CP / 4); idx += 256) {
        int row = idx / (CP / 4), c4 = idx % (CP / 4);
        int j = j0 + row;
        float4 v = make_float4(0.f, 0.f, 0.f, 0.f);
        if (j < NP) v = *(const float4*)(x + ((size_t)b * NP + j) * C + c4 * 4);
        *(float4*)(&Bs[row * STR + c4 * 4]) = v;
    }
    __syncthreads();

    float acc[4][2];
    #pragma unroll
    for (int r = 0; r < 4; ++r) { acc[r][0] = 0.f; acc[r][1] = 0.f; }
    #pragma unroll 4
    for (int k4 = 0; k4 < CP / 4; ++k4) {
        float4 b0 = *(const float4*)(&Bs[tx * STR + k4 * 4]);
        float4 b1 = *(const float4*)(&Bs[(tx + 32) * STR + k4 * 4]);
        #pragma unroll
        for (int r = 0; r < 4; ++r) {
            float4 a = *(const float4*)(&As[(ty * 4 + r) * STR + k4 * 4]);
            float d;
            d = a.x - b0.x; acc[r][0] += d * d;  d = a.x - b1.x; acc[r][1] += d * d;
            d = a.y - b0.y; acc[r][0] += d * d;  d = a.y - b1.y; acc[r][1] += d * d;
            d = a.z - b0.z; acc[r][0] += d * d;  d = a.z - b1.z; acc[r][1] += d * d;
            d = a.w - b0.w; acc[r][0] += d * d;  d = a.w - b1.w; acc[r][1] += d * d;
        }
    }

    int ja = j0 + tx, jb = j0 + tx + 32;
    #pragma unroll
    for (int r = 0; r < 4; ++r) {
        int i = i0 + ty * 4 + r;
        if (i < NP) {
            size_t base = ((size_t)b * NP + i) * NP;
            if (ja < NP) d2[base + ja] = acc[r][0];
            if (jb < NP) d2[base + jb] = acc[r][1];
        }
    }
}

// ---------------- R26: EdgeConv-2 via bf16 MFMA, with FUSED top-8 select ----------------
#define E2STR 72
__global__ __launch_bounds__(256) void ec2_mfma_kernel(
        const float* __restrict__ x1, const float* __restrict__ d2,
        const ushort* __restrict__ w1t, const ushort* __restrict__ w2t,
        const float* __restrict__ b1f, const float* __restrict__ b2f,
        float* __restrict__ x2out) {
    __shared__ ushort Elds[32 * E2STR];
    __shared__ ushort Hlds[32 * E2STR];
    __shared__ int nbl[4][KNN];
    int tid = threadIdx.x;
    int P0 = blockIdx.x * 4;

    {   // fused selection: one wave per point
        int lane = tid & 63, wave = tid >> 6;
        u64 best[KNN];
        wave_sel8(d2 + (size_t)(P0 + wave) * NP, lane, best);
        if (lane < KNN) nbl[wave][lane] = (int)(best[lane] & 0xffffffffu);
    }
    __syncthreads();

    {
        int e = tid >> 3, seg = tid & 7;
        int bi = P0 + (e >> 3), k = e & 7;
        int b = bi / NP;
        int nb = nbl[e >> 3][k];
        const float* xi = x1 + (size_t)bi * 32;
        const float* xj = x1 + ((size_t)b * NP + nb) * 32;
        int c0 = seg * 8;
        #pragma unroll
        for (int c = c0; c < c0 + 8; c += 4) {
            float4 v;
            if (c < 32) {
                v = *(const float4*)(xi + c);
            } else {
                float4 a = *(const float4*)(xi + c - 32);
                float4 q = *(const float4*)(xj + c - 32);
                v = make_float4(q.x - a.x, q.y - a.y, q.z - a.z, q.w - a.w);
            }
            uint lo = (uint)f2b(v.x) | ((uint)f2b(v.y) << 16);
            uint hi = (uint)f2b(v.z) | ((uint)f2b(v.w) << 16);
            *(uint2*)(&Elds[e * E2STR + c]) = make_uint2(lo, hi);
        }
    }
    __syncthreads();

    int lane = tid & 63, wave = tid >> 6;
    int n16 = lane & 15, quad = lane >> 4;

    {
        int nc = wave * 16;
        f32x4 acc[2];
        float bv = b1f[nc + n16];
        acc[0] = (f32x4){bv, bv, bv, bv};
        acc[1] = acc[0];
        #pragma unroll
        for (int k8 = 0; k8 < 2; ++k8) {
            int ko = k8 * 32 + quad * 8;
            short8 a0 = *(const short8*)(&Elds[(n16) * E2STR + ko]);
            short8 a1 = *(const short8*)(&Elds[(16 + n16) * E2STR + ko]);
            short8 bfr = *(const short8*)(&w1t[(size_t)(nc + n16) * 64 + ko]);
            acc[0] = __builtin_amdgcn_mfma_f32_16x16x32_bf16(a0, bfr, acc[0], 0, 0, 0);
            acc[1] = __builtin_amdgcn_mfma_f32_16x16x32_bf16(a1, bfr, acc[1], 0, 0, 0);
        }
        #pragma unroll
        for (int mt = 0; mt < 2; ++mt) {
            int col = nc + n16;
            #pragma unroll
            for (int r = 0; r < 4; ++r) {
                int row = mt * 16 + quad * 4 + r;
                Hlds[row * E2STR + col] = f2b(fmaxf(acc[mt][r], 0.f));
            }
        }
    }
    __syncthreads();

    {
        int nc2 = wave * 32;
        f32x4 acc[2][2];
        #pragma unroll
        for (int mt = 0; mt < 2; ++mt)
            #pragma unroll
            for (int nt = 0; nt < 2; ++nt) acc[mt][nt] = (f32x4){0.f, 0.f, 0.f, 0.f};
        #pragma unroll
        for (int k8 = 0; k8 < 2; ++k8) {
            int ko = k8 * 32 + quad * 8;
            short8 a0 = *(const short8*)(&Hlds[(n16) * E2STR + ko]);
            short8 a1 = *(const short8*)(&Hlds[(16 + n16) * E2STR + ko]);
            #pragma unroll
            for (int nt = 0; nt < 2; ++nt) {
                short8 bfr = *(const short8*)(&w2t[(size_t)(nc2 + nt * 16 + n16) * 64 + ko]);
                acc[0][nt] = __builtin_amdgcn_mfma_f32_16x16x32_bf16(a0, bfr, acc[0][nt], 0, 0, 0);
                acc[1][nt] = __builtin_amdgcn_mfma_f32_16x16x32_bf16(a1, bfr, acc[1][nt], 0, 0, 0);
            }
        }
        #pragma unroll
        for (int mt = 0; mt < 2; ++mt)
            #pragma unroll
            for (int nt = 0; nt < 2; ++nt) {
                f32x4 a = acc[mt][nt];
                float v = fmaxf(fmaxf(a[0], a[1]), fmaxf(a[2], a[3]));
                float o = fmaxf(v, __shfl_xor(v, 16, 64));
                int col = nc2 + nt * 16 + n16;
                if (quad == 0)
                    x2out[(size_t)(P0 + mt * 2) * 128 + col] = o + b2f[col];
                else if (quad == 2)
                    x2out[(size_t)(P0 + mt * 2 + 1) * 128 + col] = o + b2f[col];
            }
    }
}

// ---------------- R26: EdgeConv-3 via bf16 MFMA, with FUSED top-8 select ----------------
#define ESTR 264   // LDS row stride (bf16 elems)
__global__ __launch_bounds__(256) void ec3_mfma_kernel(
        const float* __restrict__ x2, const float* __restrict__ d2,
        const ushort* __restrict__ w1t, const ushort* __restrict__ w2t,
        const float* __restrict__ b1f, const float* __restrict__ b2f,
        float* __restrict__ x3) {
    __shared__ ushort Elds[32 * ESTR];
    __shared__ ushort Hlds[32 * ESTR];
    __shared__ int nbl[4][KNN];
    int tid = threadIdx.x;
    int P0 = blockIdx.x * 4;

    {   // fused selection: one wave per point
        int lane = tid & 63, wave = tid >> 6;
        u64 best[KNN];
        wave_sel8(d2 + (size_t)(P0 + wave) * NP, lane, best);
        if (lane < KNN) nbl[wave][lane] = (int)(best[lane] & 0xffffffffu);
    }
    __syncthreads();

    {
        int e = tid >> 3, seg = tid & 7;
        int bi = P0 + (e >> 3), k = e & 7;
        int b = bi / NP;
        int nb = nbl[e >> 3][k];
        const float* xi = x2 + (size_t)bi * 128;
        const float* xj = x2 + ((size_t)b * NP + nb) * 128;
        int c0 = seg * 16;
        #pragma unroll
        for (int c = c0; c < c0 + 16; c += 4) {
            float4 a = *(const float4*)(xi + c);
            float4 q = *(const float4*)(xj + c);
            uint lo = (uint)f2b(a.x) | ((uint)f2b(a.y) << 16);
            uint hi = (uint)f2b(a.z) | ((uint)f2b(a.w) << 16);
            *(uint2*)(&Elds[e * ESTR + c]) = make_uint2(lo, hi);
            lo = (uint)f2b(q.x - a.x) | ((uint)f2b(q.y - a.y) << 16);
            hi = (uint)f2b(q.z - a.z) | ((uint)f2b(q.w - a.w) << 16);
            *(uint2*)(&Elds[e * ESTR + 128 + c]) = make_uint2(lo, hi);
        }
    }
    __syncthreads();

    int lane = tid & 63, wave = tid >> 6;
    int n16 = lane & 15, quad = lane >> 4;

    {
        int nc = wave * 64;
        f32x4 acc1[2][4];
        #pragma unroll
        for (int mt = 0; mt < 2; ++mt)
            #pragma unroll
            for (int nt = 0; nt < 4; ++nt) {
                float bv = b1f[nc + nt * 16 + n16];
                acc1[mt][nt] = (f32x4){bv, bv, bv, bv};
            }
        #pragma unroll
        for (int k8 = 0; k8 < 8; ++k8) {
            int ko = k8 * 32 + quad * 8;
            short8 a0 = *(const short8*)(&Elds[(n16) * ESTR + ko]);
            short8 a1 = *(const short8*)(&Elds[(16 + n16) * ESTR + ko]);
            #pragma unroll
            for (int nt = 0; nt < 4; ++nt) {
                short8 bfr = *(const short8*)(&w1t[(size_t)(nc + nt * 16 + n16) * 256 + ko]);
                acc1[0][nt] = __builtin_amdgcn_mfma_f32_16x16x32_bf16(a0, bfr, acc1[0][nt], 0, 0, 0);
                acc1[1][nt] = __builtin_amdgcn_mfma_f32_16x16x32_bf16(a1, bfr, acc1[1][nt], 0, 0, 0);
            }
        }
        #pragma unroll
        for (int mt = 0; mt < 2; ++mt)
            #pragma unroll
            for (int nt = 0; nt < 4; ++nt) {
                int col = nc + nt * 16 + n16;
                #pragma unroll
                for (int r = 0; r < 4; ++r) {
                    int row = mt * 16 + quad * 4 + r;
                    Hlds[row * ESTR + col] = f2b(fmaxf(acc1[mt][nt][r], 0.f));
                }
            }
    }
    __syncthreads();

    {
        int nc2 = wave * 128;
        f32x4 acc2[2][8];
        #pragma unroll
        for (int mt = 0; mt < 2; ++mt)
            #pragma unroll
            for (int nt = 0; nt < 8; ++nt) acc2[mt][nt] = (f32x4){0.f, 0.f, 0.f, 0.f};
        #pragma unroll
        for (int k8 = 0; k8 < 8; ++k8) {
            int ko = k8 * 32 + quad * 8;
            short8 a0 = *(const short8*)(&Hlds[(n16) * ESTR + ko]);
            short8 a1 = *(const short8*)(&Hlds[(16 + n16) * ESTR + ko]);
            #pragma unroll
            for (int nt = 0; nt < 8; ++nt) {
                short8 bfr = *(const short8*)(&w2t[(size_t)(nc2 + nt * 16 + n16) * 256 + ko]);
                acc2[0][nt] = __builtin_amdgcn_mfma_f32_16x16x32_bf16(a0, bfr, acc2[0][nt], 0, 0, 0);
                acc2[1][nt] = __builtin_amdgcn_mfma_f32_16x16x32_bf16(a1, bfr, acc2[1][nt], 0, 0, 0);
            }
        }
        #pragma unroll
        for (int mt = 0; mt < 2; ++mt)
            #pragma unroll
            for (int nt = 0; nt < 8; ++nt) {
                f32x4 a = acc2[mt][nt];
                float v = fmaxf(fmaxf(a[0], a[1]), fmaxf(a[2], a[3]));
                float o = fmaxf(v, __shfl_xor(v, 16, 64));
                int col = nc2 + nt * 16 + n16;
                if (quad == 0)
                    x3[(size_t)(P0 + mt * 2) * 512 + col] = o + b2f[col];
                else if (quad == 2)
                    x3[(size_t)(P0 + mt * 2 + 1) * 512 + col] = o + b2f[col];
            }
    }
}

// ---------------- shared MLP + hij via bf16 MFMA, fully fused ----------------
#define XSTR 680   // 672+8 bf16
#define SSTR 136   // 128+8
__global__ __launch_bounds__(256) void sm_mfma_kernel(
        const float* __restrict__ x1, const float* __restrict__ x2,
        const float* __restrict__ x3,
        const ushort* __restrict__ w1t, const ushort* __restrict__ w2t,
        const ushort* __restrict__ ecw1t,
        const float* __restrict__ b1f, const float* __restrict__ b2f,
        float* __restrict__ sf, float* __restrict__ hi, float* __restrict__ hj) {
    __shared__ ushort Xlds[32 * XSTR];
    __shared__ ushort Hlds[32 * ESTR];
    __shared__ ushort Slds[32 * SSTR];
    int tid = threadIdx.x;
    int P0 = blockIdx.x * 32;

    {
        int row = tid >> 3, cseg = tid & 7;
        int p = P0 + row;
        bool ok = p < NB * NP;
        #pragma unroll
        for (int k = 0; k < 21; ++k) {
            int c = cseg * 4 + k * 32;
            float4 v = make_float4(0.f, 0.f, 0.f, 0.f);
            if (ok) {
                if (c < 32) v = *(const float4*)(x1 + (size_t)p * 32 + c);
                else if (c < 160) v = *(const float4*)(x2 + (size_t)p * 128 + (c - 32));
                else v = *(const float4*)(x3 + (size_t)p * 512 + (c - 160));
            }
            uint lo = (uint)f2b(v.x) | ((uint)f2b(v.y) << 16);
            uint hv = (uint)f2b(v.z) | ((uint)f2b(v.w) << 16);
            *(uint2*)(&Xlds[row * XSTR + c]) = make_uint2(lo, hv);
        }
    }
    __syncthreads();

    int lane = tid & 63, wave = tid >> 6;
    int n16 = lane & 15, quad = lane >> 4;

    {
        int nc = wave * 64;
        f32x4 acc[2][4];
        #pragma unroll
        for (int mt = 0; mt < 2; ++mt)
            #pragma unroll
            for (int nt = 0; nt < 4; ++nt) {
                float bv = b1f[nc + nt * 16 + n16];
                acc[mt][nt] = (f32x4){bv, bv, bv, bv};
            }
        #pragma unroll
        for (int k8 = 0; k8 < 21; ++k8) {
            int ko = k8 * 32 + quad * 8;
            short8 a0 = *(const short8*)(&Xlds[(n16) * XSTR + ko]);
            short8 a1 = *(const short8*)(&Xlds[(16 + n16) * XSTR + ko]);
            #pragma unroll
            for (int nt = 0; nt < 4; ++nt) {
                short8 bfr = *(const short8*)(&w1t[(size_t)(nc + nt * 16 + n16) * 672 + ko]);
                acc[0][nt] = __builtin_amdgcn_mfma_f32_16x16x32_bf16(a0, bfr, acc[0][nt], 0, 0, 0);
                acc[1][nt] = __builtin_amdgcn_mfma_f32_16x16x32_bf16(a1, bfr, acc[1][nt], 0, 0, 0);
            }
        }
        #pragma unroll
        for (int mt = 0; mt < 2; ++mt)
            #pragma unroll
            for (int nt = 0; nt < 4; ++nt) {
                int col = nc + nt * 16 + n16;
                #pragma unroll
                for (int r = 0; r < 4; ++r) {
                    int row = mt * 16 + quad * 4 + r;
                    Hlds[row * ESTR + col] = f2b(fmaxf(acc[mt][nt][r], 0.f));
                }
            }
    }
    __syncthreads();

    {
        int nc = wave * 32;
        f32x4 acc[2][2];
        #pragma unroll
        for (int mt = 0; mt < 2; ++mt)
            #pragma unroll
            for (int nt = 0; nt < 2; ++nt) {
                float bv = b2f[nc + nt * 16 + n16];
                acc[mt][nt] = (f32x4){bv, bv, bv, bv};
            }
        #pragma unroll
        for (int k8 = 0; k8 < 8; ++k8) {
            int ko = k8 * 32 + quad * 8;
            short8 a0 = *(const short8*)(&Hlds[(n16) * ESTR + ko]);
            short8 a1 = *(const short8*)(&Hlds[(16 + n16) * ESTR + ko]);
            #pragma unroll
            for (int nt = 0; nt < 2; ++nt) {
                short8 bfr = *(const short8*)(&w2t[(size_t)(nc + nt * 16 + n16) * 256 + ko]);
                acc[0][nt] = __builtin_amdgcn_mfma_f32_16x16x32_bf16(a0, bfr, acc[0][nt], 0, 0, 0);
                acc[1][nt] = __builtin_amdgcn_mfma_f32_16x16x32_bf16(a1, bfr, acc[1][nt], 0, 0, 0);
            }
        }
        #pragma unroll
        for (int mt = 0; mt < 2; ++mt)
            #pragma unroll
            for (int nt = 0; nt < 2; ++nt) {
                int col = nc + nt * 16 + n16;
                #pragma unroll
                for (int r = 0; r < 4; ++r) {
                    int row = mt * 16 + quad * 4 + r;
                    int p = P0 + row;
                    float v = acc[mt][nt][r];
                    if (p < NB * NP) sf[(size_t)p * 128 + col] = v;
                    Slds[row * SSTR + col] = f2b(v);
                }
            }
    }
    __syncthreads();

    {
        int nc = wave * 64;
        f32x4 acc[2][4];
        #pragma unroll
        for (int mt = 0; mt < 2; ++mt)
            #pragma unroll
            for (int nt = 0; nt < 4; ++nt) acc[mt][nt] = (f32x4){0.f, 0.f, 0.f, 0.f};
        #pragma unroll
        for (int k8 = 0; k8 < 4; ++k8) {
            int ko = k8 * 32 + quad * 8;
            short8 a0 = *(const short8*)(&Slds[(n16) * SSTR + ko]);
            short8 a1 = *(const short8*)(&Slds[(16 + n16) * SSTR + ko]);
            #pragma unroll
            for (int nt = 0; nt < 4; ++nt) {
                short8 bfr = *(const short8*)(&ecw1t[(size_t)(nc + nt * 16 + n16) * 128 + ko]);
                acc[0][nt] = __builtin_amdgcn_mfma_f32_16x16x32_bf16(a0, bfr, acc[0][nt], 0, 0, 0);
                acc[1][nt] = __builtin_amdgcn_mfma_f32_16x16x32_bf16(a1, bfr, acc[1][nt], 0, 0, 0);
            }
        }
        #pragma unroll
        for (int mt = 0; mt < 2; ++mt)
            #pragma unroll
            for (int nt = 0; nt < 4; ++nt) {
                int colp = nc + nt * 16 + n16;
                float* dst = (colp < 128) ? hi : hj;
                int col = colp & 127;
                #pragma unroll
                for (int r = 0; r < 4; ++r) {
                    int row = mt * 16 + quad * 4 + r;
                    int p = P0 + row;
                    if (p < NB * NP) dst[(size_t)p * 128 + col] = acc[mt][nt][r];
                }
            }
    }
}

// ---------------- R27: fused global max pool + hg projection (one block per batch) ----
// Replaces gmax1 (50 blk) + gfin (2 blk): 256 threads = 128 cols x 2 halves;
// halves split the 1000-row max and the 128-term dot, combined via LDS. Max is
// order-exact; dot reassociation is ulp-level.
__global__ __launch_bounds__(256) void gpool_kernel(
        const float* __restrict__ sf, const float* __restrict__ w1,
        const float* __restrict__ b1, float* __restrict__ hg) {
    int b = blockIdx.x;
    int o = threadIdx.x & 127, half = threadIdx.x >> 7;
    __shared__ float red[2][128];
    __shared__ float gs[128];
    __shared__ float part[2][128];
    float v = -INFINITY;
    int n0 = half * 500;
    for (int n = n0; n < n0 + 500; ++n)
        v = fmaxf(v, sf[((size_t)b * NP + n) * 128 + o]);
    red[half][o] = v;
    __syncthreads();
    if (half == 0) gs[o] = fmaxf(red[0][o], red[1][o]);
    __syncthreads();
    float acc = 0.f;
    int c0 = half * 64;
    for (int c = c0; c < c0 + 64; ++c)
        acc += gs[c] * w1[(256 + c) * 128 + o];
    part[half][o] = acc;
    __syncthreads();
    if (half == 0) hg[b * 128 + o] = b1[o] + part[0][o] + part[1][o];
}

// ---------------- pairwise scorer: R17 structure (best measured total) ----------------
#define PLD(o4, A_, H0_, H1_, W_)                                              \
    {                                                                          \
        W_  = *(const float4*)(&w2s[(o4) * 4]);                                \
        H0_ = *(const float4*)(&hjt[tj][(o4) * 4]);                            \
        H1_ = *(const float4*)(&hjt[tj + 32][(o4) * 4]);                       \
        _Pragma("unroll")                                                      \
        for (int r = 0; r < 4; ++r)                                            \
            A_[r] = *(const float4*)(&hit[ti3 * 4 + r][(o4) * 4]);             \
    }
#define PCOMP(A_, H0_, H1_, W_)                                                \
    {                                                                          \
        _Pragma("unroll")                                                      \
        for (int r = 0; r < 4; ++r) {                                          \
            float4 a = A_[r];                                                  \
            acc[r][0] += fmaxf(a.x + H0_.x, 0.f) * W_.x                        \
                       + fmaxf(a.y + H0_.y, 0.f) * W_.y                        \
                       + fmaxf(a.z + H0_.z, 0.f) * W_.z                        \
                       + fmaxf(a.w + H0_.w, 0.f) * W_.w;                       \
            acc[r][1] += fmaxf(a.x + H1_.x, 0.f) * W_.x                        \
                       + fmaxf(a.y + H1_.y, 0.f) * W_.y                        \
                       + fmaxf(a.z + H1_.z, 0.f) * W_.z                        \
                       + fmaxf(a.w + H1_.w, 0.f) * W_.w;                       \
        }                                                                      \
    }

__global__ __launch_bounds__(256) void pair_kernel(
        const float* __restrict__ hi, const float* __restrict__ hj,
        const float* __restrict__ hg,
        const float* __restrict__ w2, const float* __restrict__ b2,
        void* __restrict__ out, const int* __restrict__ flag) {
    int j0 = blockIdx.x * 64, i0 = blockIdx.y * 32, b = blockIdx.z;
    if (j0 + 63 <= i0) return;    // no j > i possible in this tile
    __shared__ float hit[32][132];
    __shared__ float hjt[64][132];
    __shared__ __align__(16) float w2s[128];
    int tid = threadIdx.x;
    if (tid < 128) w2s[tid] = w2[tid];
    int c4 = tid & 31;   // fixed per thread (stride 256 = 8 rows)
    float4 hgv = *(const float4*)(hg + b * 128 + c4 * 4);
    for (int t = tid; t < 96 * 32; t += 256) {
        int row = t >> 5;
        if (row < 32) {
            int i = i0 + row;
            float4 v = make_float4(0.f, 0.f, 0.f, 0.f);
            if (i < NP) v = *(const float4*)(hi + ((size_t)b * NP + i) * 128 + c4 * 4);
            *(float4*)(&hit[row][c4 * 4]) = v;
        } else {
            int j = j0 + row - 32;
            float4 v = make_float4(0.f, 0.f, 0.f, 0.f);
            if (j < NP) v = *(const float4*)(hj + ((size_t)b * NP + j) * 128 + c4 * 4);
            *(float4*)(&hjt[row - 32][c4 * 4]) =
                make_float4(v.x + hgv.x, v.y + hgv.y, v.z + hgv.z, v.w + hgv.w);
        }
    }
    __syncthreads();

    int tj = tid & 31;       // 32 j-lanes (rows tj / tj+32 of hjt)
    int ti3 = tid >> 5;      // 8 i-groups of 4 rows
    float acc[4][2] = {{0.f, 0.f}, {0.f, 0.f}, {0.f, 0.f}, {0.f, 0.f}};

    // 2-stage software pipeline: o4+1's 7 LDS loads issued before o4's compute retires
    float4 A0[4], H00, H01, W0;
    float4 A1[4], H10, H11, W1;
    PLD(0, A0, H00, H01, W0)
    for (int o = 0; o < 32; o += 2) {
        PLD(o + 1, A1, H10, H11, W1)
        PCOMP(A0, H00, H01, W0)
        if (o + 2 < 32) PLD(o + 2, A0, H00, H01, W0)
        PCOMP(A1, H10, H11, W1)
    }

    float bb = b2[0];
    int f = flag[0];
    #pragma unroll
    for (int r = 0; r < 4; ++r) {
        int i = i0 + ti3 * 4 + r;
        #pragma unroll
        for (int jj = 0; jj < 2; ++jj) {
            int j = j0 + tj + jj * 32;
            if (i < j && j < NP) {
                size_t p = (size_t)i * (NP - 1) - (size_t)i * (i - 1) / 2 + (j - i - 1);
                float mo = acc[r][jj] + bb;
                float pr = 1.f / (1.f + expf(-mo));
                size_t idx0 = (size_t)b * PPAIR + p;
                size_t idx1 = (size_t)NB * PPAIR + idx0;
                if (f) {
                    ((float*)out)[idx0] = pr;
                    ((float*)out)[idx1] = mo;
                } else {
                    ((bf16*)out)[idx0] = __float2bfloat16(pr);
                    ((bf16*)out)[idx1] = __float2bfloat16(mo);
                }
            }
        }
    }
}

extern "C" void kernel_launch(void* const* d_in, const int* in_sizes, int n_in,
                              void* d_out, int out_size, void* d_ws, size_t ws_size,
                              hipStream_t stream) {
    float* ws = (float*)d_ws;
    float* posf = ws + OFF_POS;
    float* x1   = ws + OFF_X1;
    float* x2   = ws + OFF_X2;
    float* x3   = ws + OFF_X3;
    float* sf   = ws + OFF_SF;
    float* hi   = ws + OFF_HI;
    float* hj   = ws + OFF_HJ;
    float* hgb  = ws + OFF_HG;
    int*   flag = (int*)(ws + OFF_FLAG);
    float* d2m  = ws + OFF_D2;
    ushort* w1t = (ushort*)(ws + OFF_W1T);
    ushort* w2t = (ushort*)(ws + OFF_W2T);
    ushort* smw1t = (ushort*)(ws + OFF_SMW1T);
    ushort* smw2t = (ushort*)(ws + OFF_SMW2T);
    ushort* ecw1t = (ushort*)(ws + OFF_ECW1T);
    ushort* e2w1t = (ushort*)(ws + OFF_E2W1T);
    ushort* e2w2t = (ushort*)(ws + OFF_E2W2T);

    // 1) detect input dtype (bf16 vs f32) on-device
    detect_kernel<<<1, 256, 0, stream>>>(d_in[0], flag);

    // 2) convert all inputs to f32 + build all transposed bf16 weights
    //    (flattened 1-D grid: 3591 working blocks)
    InPtrs ip;
    for (int i = 0; i < 21; ++i) ip.p[i] = d_in[i];
    cvt_all_kernel<<<3591, 256, 0, stream>>>(ip, ws, flag, w1t, w2t, smw1t, smw2t,
                                             ecw1t, e2w1t, e2w2t);

    dim3 kgrid_f(NP / 8, NB);                      // fused knn<3>+ec1
    dim3 dgrid(32, 16, 2);                          // dist tiles: 32x64, 2 batches

    // 3) EdgeConv 1 (C=3 -> 32): fused kNN + wave-per-point EdgeConv
    knn_ec1_kernel<<<kgrid_f, 256, 0, stream>>>(
        posf, ws + OFF_C1W1, ws + OFF_C1B1, ws + OFF_C1W2, ws + OFF_C1B2, x1);

    // 4) EdgeConv 2 (C=32 -> 128): dist matrix + fused select+MFMA
    dist_kernel<32><<<dgrid, 256, 0, stream>>>(x1, d2m);
    ec2_mfma_kernel<<<NB * NP / 4, 256, 0, stream>>>(
        x1, d2m, e2w1t, e2w2t, ws + OFF_C2B1, ws + OFF_C2B2, x2);

    // 5) EdgeConv 3 (C=128 -> 512): dist matrix + fused select+MFMA
    dist_kernel<128><<<dgrid, 256, 0, stream>>>(x2, d2m);
    ec3_mfma_kernel<<<NB * NP / 4, 256, 0, stream>>>(
        x2, d2m, w1t, w2t, ws + OFF_C3B1, ws + OFF_C3B2, x3);

    // 6) shared MLP + hij via MFMA -> sf, hi, hj
    sm_mfma_kernel<<<(NB * NP + 31) / 32, 256, 0, stream>>>(
        x1, x2, x3, smw1t, smw2t, ecw1t, ws + OFF_SMB1, ws + OFF_SMB2, sf, hi, hj);

    // 7) fused global max pool + hg projection (one block per batch)
    gpool_kernel<<<NB, 256, 0, stream>>>(sf, ws + OFF_ECW1, ws + OFF_ECB1, hgb);

    // 8) pairwise scorer (R17 structure: 32x64 tiles, f32, 2-stage pipeline)
    dim3 pgrid(16, 32, NB);
    pair_kernel<<<pgrid, 256, 0, stream>>>(hi, hj, hgb, ws + OFF_ECW2, ws + OFF_ECB2,
                                           d_out, flag);
}

// Round 13
// 266.669 us; speedup vs baseline: 1.2991x; 1.2991x over previous
//
#include <hip/hip_runtime.h>
#include <hip/hip_bf16.h>
#include <cmath>

// Problem constants (B=2, N=1000, k=8 from reference)
#define NB 2
#define NP 1000
#define KNN 8
#define PPAIR 499500  // N*(N-1)/2

typedef __hip_bfloat16 bf16;
typedef unsigned long long u64;
typedef unsigned short ushort;
typedef unsigned int uint;
typedef __attribute__((ext_vector_type(8))) short short8;
typedef __attribute__((ext_vector_type(4))) float f32x4;

__device__ __forceinline__ float b2f(bf16 v) { return __bfloat162float(v); }
// f32 -> bf16 bits, round-to-nearest-even
__device__ __forceinline__ ushort f2b(float f) {
    uint x = __float_as_uint(f);
    return (ushort)((x + 0x7FFFu + ((x >> 16) & 1u)) >> 16);
}
// flag-aware element load from an input buffer
__device__ __forceinline__ float ldin(const void* p, int flag, int i) {
    return flag ? ((const float*)p)[i] : b2f(((const bf16*)p)[i]);
}

// Workspace layout (float offsets), all 16B-aligned
#define OFF_POS    0
#define OFF_C1W1   6000
#define OFF_C1B1   6096
#define OFF_C1W2   6112
#define OFF_C1B2   6624
#define OFF_C2W1   6656
#define OFF_C2B1   10752
#define OFF_C2W2   10816
#define OFF_C2B2   19008
#define OFF_C3W1   19136
#define OFF_C3B1   84672
#define OFF_C3W2   84928
#define OFF_C3B2   216000
#define OFF_SMW1   216512
#define OFF_SMB1   388544
#define OFF_SMW2   388800
#define OFF_SMB2   421568
#define OFF_ECW1   421696
#define OFF_ECB1   470848
#define OFF_ECW2   470976
#define OFF_ECB2   471104
#define OFF_X1     471112
#define OFF_X2     535112
#define OFF_X3     791112
#define OFF_SF     1815112
#define OFF_G      2071112
#define OFF_HI     2071368
#define OFF_HJ     2327368
#define OFF_HG     2583368
#define OFF_FLAG   2583624   // int
#define OFF_NIDX   2583632   // (unused since R27: knn<3> result stays in LDS)
#define OFF_GP     2599632   // 50*128 partial max (restored R28)
#define OFF_W1T    2606032   // ec3 W1T 256x256 bf16 (32768 f32)
#define OFF_W2T    2638800   // ec3 W2T 512x256 bf16 (65536 f32)
#define OFF_SMW1T  2704336   // sm W1T 256x672 bf16 (86016 f32)
#define OFF_SMW2T  2790352   // sm W2T 128x256 bf16 (16384 f32)
#define OFF_ECW1T  2806736   // hij WT 256x128 bf16 (16384 f32)
#define OFF_PL     2823120   // (unused since R16)
#define OFF_E2W1T  3079120   // ec2 W1T 64x64 bf16 (2048 f32)
#define OFF_E2W2T  3081168   // ec2 W2T 128x64 bf16 (4096 f32)
#define OFF_D2     3085264   // full d2 matrix [NB][NP][NP] f32 (2,000,000 f32)

// ---------------- dtype detection ----------------
__global__ void detect_kernel(const void* pos, int* flag) {
    __shared__ float red[256];
    const unsigned short* p = (const unsigned short*)pos;
    float m = 0.f;
    for (int t = threadIdx.x; t < 6000; t += 256) {
        unsigned int u = ((unsigned int)p[t]) << 16;
        float v = fabsf(__uint_as_float(u));
        if (!isfinite(v)) v = 1e30f;
        m = fmaxf(m, v);
    }
    red[threadIdx.x] = m;
    __syncthreads();
    for (int s = 128; s > 0; s >>= 1) {
        if (threadIdx.x < s) red[threadIdx.x] = fmaxf(red[threadIdx.x], red[threadIdx.x + s]);
        __syncthreads();
    }
    if (threadIdx.x == 0) flag[0] = (red[0] > 1e6f) ? 1 : 0;
}

// ---------------- convert inputs to f32 + build transposed bf16 weights ----------------
// R24: flattened 1-D grid (3591 working blocks) instead of 672x28=18816.
struct InPtrs { const void* p[21]; };

#define CVT_NSEG 28
__global__ void cvt_all_kernel(InPtrs in, float* ws, const int* flag,
                               ushort* w1t, ushort* w2t, ushort* smw1t,
                               ushort* smw2t, ushort* ecw1t,
                               ushort* e2w1t, ushort* e2w2t) {
    const int sizes[21] = {6000, 96, 16, 512, 32, 4096, 64, 8192, 128,
                           65536, 256, 131072, 512, 172032, 256, 32768, 128,
                           49152, 128, 128, 1};
    const int offs[21] = {OFF_POS, OFF_C1W1, OFF_C1B1, OFF_C1W2, OFF_C1B2,
                          OFF_C2W1, OFF_C2B1, OFF_C2W2, OFF_C2B2,
                          OFF_C3W1, OFF_C3B1, OFF_C3W2, OFF_C3B2,
                          OFF_SMW1, OFF_SMB1, OFF_SMW2, OFF_SMB2,
                          OFF_ECW1, OFF_ECB1, OFF_ECW2, OFF_ECB2};
    // cumulative block counts per segment (ceil(size/256)); see launch grid
    const int cum[CVT_NSEG + 1] = {0, 24, 25, 26, 28, 29, 45, 46, 78, 79, 335,
                                   336, 848, 850, 1522, 1523, 1651, 1652, 1844,
                                   1845, 1846, 1847, 2103, 2615, 3287, 3415,
                                   3543, 3559, 3591};
    int bid = blockIdx.x;
    int y = 0;
    while (y < CVT_NSEG - 1 && bid >= cum[y + 1]) ++y;   // uniform scalar scan
    int t = (bid - cum[y]) * 256 + threadIdx.x;
    int f = flag[0];
    if (y < 21) {
        if (t < sizes[y]) ws[offs[y] + t] = ldin(in.p[y], f, t);
    } else if (y == 21) {
        if (t < 65536) {            // ec3 W1 [c=256][h=256] -> [h][c]
            int h = t >> 8, c = t & 255;
            w1t[t] = f2b(ldin(in.p[9], f, c * 256 + h));
        }
    } else if (y == 22) {
        if (t < 131072) {           // ec3 W2 [h=256][o=512] -> [o][h]
            int o = t >> 8, h = t & 255;
            w2t[t] = f2b(ldin(in.p[11], f, h * 512 + o));
        }
    } else if (y == 23) {
        if (t < 172032) {           // sm W1 [c=672][h=256] -> [h][c]
            int h = t / 672, c = t - h * 672;
            smw1t[t] = f2b(ldin(in.p[13], f, c * 256 + h));
        }
    } else if (y == 24) {
        if (t < 32768) {            // sm W2 [h=256][o=128] -> [o][h]
            int o = t >> 8, h = t & 255;
            smw2t[t] = f2b(ldin(in.p[15], f, h * 128 + o));
        }
    } else if (y == 25) {
        if (t < 32768) {            // ec W1[:256] -> [o'][c]
            int op = t >> 7, c = t & 127;
            int idx = (op < 128) ? (c * 128 + op) : ((128 + c) * 128 + (op - 128));
            ecw1t[t] = f2b(ldin(in.p[17], f, idx));
        }
    } else if (y == 26) {
        if (t < 4096) {             // ec2 W1 [c=64][h=64] -> [h][c]
            int h = t >> 6, c = t & 63;
            e2w1t[t] = f2b(ldin(in.p[5], f, c * 64 + h));
        }
    } else {
        if (t < 8192) {             // ec2 W2 [h=64][o=128] -> [o][h]
            int o = t >> 6, h = t & 63;
            e2w2t[t] = f2b(ldin(in.p[7], f, h * 128 + o));
        }
    }
}

// ---------------- shared kNN helpers ----------------
__device__ __forceinline__ void ce(u64& a, u64& b) {
    u64 lo = a < b ? a : b;
    u64 hi = a < b ? b : a;
    a = lo; b = hi;
}

__device__ __forceinline__ u64 umin64(u64 a, u64 b) { return a < b ? a : b; }

__device__ __forceinline__ void ins8(u64 (&best)[KNN], u64 cand) {
    u64 cur = cand;
    #pragma unroll
    for (int r = 0; r < KNN; ++r) {
        u64 lo = best[r] < cur ? best[r] : cur;
        u64 hi = best[r] < cur ? cur : best[r];
        best[r] = lo; cur = hi;
    }
}

// sort 4 candidates asc, then bitonic-merge into sorted-asc best[8] (keep low 8)
__device__ __forceinline__ void merge4(u64 (&best)[KNN], u64 s0, u64 s1, u64 s2, u64 s3) {
    ce(s0, s1); ce(s2, s3); ce(s0, s2); ce(s1, s3); ce(s1, s2);   // sort4 asc
    best[4] = umin64(best[4], s3);
    best[5] = umin64(best[5], s2);
    best[6] = umin64(best[6], s1);
    best[7] = umin64(best[7], s0);
    ce(best[0], best[4]); ce(best[1], best[5]); ce(best[2], best[6]); ce(best[3], best[7]);
    ce(best[0], best[2]); ce(best[1], best[3]); ce(best[4], best[6]); ce(best[5], best[7]);
    ce(best[0], best[1]); ce(best[2], best[3]); ce(best[4], best[5]); ce(best[6], best[7]);
}

// R26: wave-level top-8 select for query q from its d2 row (knn_sel body, relocated)
__device__ __forceinline__ void wave_sel8(const float* __restrict__ row, int lane,
                                          u64 (&best)[KNN]) {
    #pragma unroll
    for (int r = 0; r < KNN; ++r) best[r] = ~0ull;
    #pragma unroll
    for (int t = 0; t < 4; ++t) {
        int j = t * 256 + lane * 4;
        if (j < NP) {   // NP%4==0 so j<NP implies j+3<NP
            float4 v = *(const float4*)(row + j);
            merge4(best,
                   (((u64)__float_as_uint(v.x)) << 32) | (unsigned)(j + 0),
                   (((u64)__float_as_uint(v.y)) << 32) | (unsigned)(j + 1),
                   (((u64)__float_as_uint(v.z)) << 32) | (unsigned)(j + 2),
                   (((u64)__float_as_uint(v.w)) << 32) | (unsigned)(j + 3));
        }
    }
    #pragma unroll
    for (int m = 1; m < 64; m <<= 1) {
        u64 other[KNN];
        #pragma unroll
        for (int r = 0; r < KNN; ++r)
            other[r] = __shfl_xor((unsigned long long)best[r], m, 64);
        u64 v[KNN];
        #pragma unroll
        for (int r = 0; r < KNN; ++r)
            v[r] = umin64(best[r], other[KNN - 1 - r]);
        ce(v[0], v[4]); ce(v[1], v[5]); ce(v[2], v[6]); ce(v[3], v[7]);
        ce(v[0], v[2]); ce(v[1], v[3]); ce(v[4], v[6]); ce(v[5], v[7]);
        ce(v[0], v[1]); ce(v[2], v[3]); ce(v[4], v[5]); ce(v[6], v[7]);
        #pragma unroll
        for (int r = 0; r < KNN; ++r) best[r] = v[r];
    }
}

// ---------------- R27: fused kNN(C=3) + EdgeConv-1 ----------------
// Phase 1: R7-proven knn_fused<3> body; top-8 kept in LDS nbl (order irrelevant:
// EdgeConv max-aggregates over neighbors). Phase 2: R25-proven wave-per-point ec1,
// looped twice (8 points/block, 4 waves). Removes ec1 launch + nidx round-trip.
__global__ __launch_bounds__(256) void knn_ec1_kernel(
        const float* __restrict__ x,
        const float* __restrict__ w1, const float* __restrict__ b1,
        const float* __restrict__ w2, const float* __restrict__ b2,
        float* __restrict__ y) {
    constexpr int C = 3, CP = 4, PSTR = 8;
    __shared__ float Qs[8 * PSTR];
    __shared__ float Ps[64 * PSTR];
    __shared__ int nbl[8][KNN];
    __shared__ float hid[4][8][17];
    int tid = threadIdx.x;
    int b = blockIdx.y;
    int i0 = blockIdx.x * 8;             // grid.x = 125 -> i0+7 <= 999 always
    int q = tid >> 5;
    int jcol = tid & 31;

    for (int idx = tid; idx < 8 * CP; idx += 256) {
        int row = idx / CP, c = idx % CP;
        int i = i0 + row;
        Qs[row * PSTR + c] = (c < C) ? x[((size_t)b * NP + i) * C + c] : 0.f;
    }

    u64 best[KNN];
    #pragma unroll
    for (int r = 0; r < KNN; ++r) best[r] = ~0ull;

    for (int jc = 0; jc < 16; ++jc) {
        int j0 = jc * 64;
        __syncthreads();
        for (int idx = tid; idx < 64 * CP; idx += 256) {
            int row = idx / CP, c = idx % CP;
            int j = j0 + row;
            Ps[row * PSTR + c] = (c < C && j < NP) ? x[((size_t)b * NP + j) * C + c] : 0.f;
        }
        __syncthreads();
        float d0 = 0.f, d1 = 0.f;
        {
            float4 qv = *(const float4*)(&Qs[q * PSTR]);
            float4 p0 = *(const float4*)(&Ps[jcol * PSTR]);
            float4 p1 = *(const float4*)(&Ps[(jcol + 32) * PSTR]);
            float t;
            t = qv.x - p0.x; d0 += t * t;  t = qv.y - p0.y; d0 += t * t;
            t = qv.z - p0.z; d0 += t * t;  t = qv.w - p0.w; d0 += t * t;
            t = qv.x - p1.x; d1 += t * t;  t = qv.y - p1.y; d1 += t * t;
            t = qv.z - p1.z; d1 += t * t;  t = qv.w - p1.w; d1 += t * t;
        }
        int ja = j0 + jcol, jb = j0 + jcol + 32;
        u64 ca = (ja < NP) ? ((((u64)__float_as_uint(d0)) << 32) | (unsigned)ja) : ~0ull;
        u64 cb = (jb < NP) ? ((((u64)__float_as_uint(d1)) << 32) | (unsigned)jb) : ~0ull;
        ins8(best, ca);
        ins8(best, cb);
    }

    #pragma unroll
    for (int m = 1; m < 32; m <<= 1) {
        u64 other[KNN];
        #pragma unroll
        for (int r = 0; r < KNN; ++r)
            other[r] = __shfl_xor((unsigned long long)best[r], m, 64);
        u64 v[KNN];
        #pragma unroll
        for (int r = 0; r < KNN; ++r)
            v[r] = best[r] < other[7 - r] ? best[r] : other[7 - r];
        ce(v[0], v[4]); ce(v[1], v[5]); ce(v[2], v[6]); ce(v[3], v[7]);
        ce(v[0], v[2]); ce(v[1], v[3]); ce(v[4], v[6]); ce(v[5], v[7]);
        ce(v[0], v[1]); ce(v[2], v[3]); ce(v[4], v[5]); ce(v[6], v[7]);
        #pragma unroll
        for (int r = 0; r < KNN; ++r) best[r] = v[r];
    }

    if (jcol == 0) {
        #pragma unroll
        for (int r = 0; r < KNN; ++r)
            nbl[q][r] = (int)(best[r] & 0xffffffffu);
    }
    __syncthreads();

    // ---- ec1 phase: wave per point, 2 points per wave ----
    int wave = tid >> 6, lane = tid & 63;
    int h = lane & 15, k2 = lane >> 4;       // k2 in 0..3
    int o = lane & 31, half = lane >> 5;
    #pragma unroll
    for (int p2 = 0; p2 < 2; ++p2) {
        int qq = p2 * 4 + wave;
        int pi = i0 + qq;
        const float* xi = x + ((size_t)b * NP + pi) * 3;
        float xi0 = xi[0], xi1 = xi[1], xi2 = xi[2];
        int nbA = nbl[qq][k2];
        int nbB = nbl[qq][k2 + 4];
        const float* xjA = x + ((size_t)b * NP + nbA) * 3;
        const float* xjB = x + ((size_t)b * NP + nbB) * 3;
        float dA0 = xjA[0] - xi0, dA1 = xjA[1] - xi1, dA2 = xjA[2] - xi2;
        float dB0 = xjB[0] - xi0, dB1 = xjB[1] - xi1, dB2 = xjB[2] - xi2;
        float wa0 = w1[h], wa1 = w1[16 + h], wa2 = w1[32 + h];
        float wb0 = w1[48 + h], wb1 = w1[64 + h], wb2 = w1[80 + h];
        float common = b1[h] + xi0 * wa0 + xi1 * wa1 + xi2 * wa2;
        hid[wave][k2][h]     = fmaxf(common + dA0 * wb0 + dA1 * wb1 + dA2 * wb2, 0.f);
        hid[wave][k2 + 4][h] = fmaxf(common + dB0 * wb0 + dB1 * wb1 + dB2 * wb2, 0.f);
        __syncthreads();
        float m = -INFINITY;
        #pragma unroll
        for (int kk = 0; kk < 4; ++kk) {
            int k = half * 4 + kk;
            float acc = 0.f;
            #pragma unroll
            for (int hh = 0; hh < 16; ++hh)
                acc += hid[wave][k][hh] * w2[hh * 32 + o];
            m = fmaxf(m, acc);
        }
        m = fmaxf(m, __shfl_xor(m, 32, 64));
        if (half == 0) y[((size_t)b * NP + pi) * 32 + o] = m + b2[o];
        __syncthreads();
    }
}

// ---------------- R16: distance-matrix kernel ----------------
template <int C>
__global__ __launch_bounds__(256) void dist_kernel(const float* __restrict__ x,
                                                   float* __restrict__ d2) {
    constexpr int CP = (C + 3) & ~3;
    constexpr int STR = CP + 4;
    __shared__ float As[32 * STR];
    __shared__ float Bs[64 * STR];
    int tid = threadIdx.x;
    int tx = tid & 31, ty = tid >> 5;
    int b = blockIdx.z;
    int i0 = blockIdx.x * 32;
    int j0 = blockIdx.y * 64;

    for (int idx = tid; idx < 32 * (CP / 4); idx += 256) {
        int row = idx / (CP / 4), c4 = idx % (CP / 4);
        int i = i0 + row;
        float4 v = make_float4(0.f, 0.f, 0.f, 0.f);
        if (i < NP) v = *(const float4*)(x + ((size_t)b * NP + i) * C + c4 * 4);
        *(float4*)(&As[row * STR + c4 * 4]) = v;
    }
    for (int idx = tid; idx < 64 * (CP / 4); idx += 256) {
        int row = idx / (CP / 4), c4 = idx % (CP / 4);
        int j = j0 + row;
        float4 v = make_float4(0.f, 0.f, 0.f, 0.f);
        if (j < NP) v = *(const float4*)(x + ((size_t)b * NP + j) * C + c4 * 4);
        *(float4*)(&Bs[row * STR + c4 * 4]) = v;
    }
    __syncthreads();

    float acc[4][2];
    #pragma unroll
    for (int r = 0; r < 4; ++r) { acc[r][0] = 0.f; acc[r][1] = 0.f; }
    #pragma unroll 4
    for (int k4 = 0; k4 < CP / 4; ++k4) {
        float4 b0 = *(const float4*)(&Bs[tx * STR + k4 * 4]);
        float4 b1 = *(const float4*)(&Bs[(tx + 32) * STR + k4 * 4]);
        #pragma unroll
        for (int r = 0; r < 4; ++r) {
            float4 a = *(const float4*)(&As[(ty * 4 + r) * STR + k4 * 4]);
            float d;
            d = a.x - b0.x; acc[r][0] += d * d;  d = a.x - b1.x; acc[r][1] += d * d;
            d = a.y - b0.y; acc[r][0] += d * d;  d = a.y - b1.y; acc[r][1] += d * d;
            d = a.z - b0.z; acc[r][0] += d * d;  d = a.z - b1.z; acc[r][1] += d * d;
            d = a.w - b0.w; acc[r][0] += d * d;  d = a.w - b1.w; acc[r][1] += d * d;
        }
    }

    int ja = j0 + tx, jb = j0 + tx + 32;
    #pragma unroll
    for (int r = 0; r < 4; ++r) {
        int i = i0 + ty * 4 + r;
        if (i < NP) {
            size_t base = ((size_t)b * NP + i) * NP;
            if (ja < NP) d2[base + ja] = acc[r][0];
            if (jb < NP) d2[base + jb] = acc[r][1];
        }
    }
}

// ---------------- R26: EdgeConv-2 via bf16 MFMA, with FUSED top-8 select ----------------
#define E2STR 72
__global__ __launch_bounds__(256) void ec2_mfma_kernel(
        const float* __restrict__ x1, const float* __restrict__ d2,
        const ushort* __restrict__ w1t, const ushort* __restrict__ w2t,
        const float* __restrict__ b1f, const float* __restrict__ b2f,
        float* __restrict__ x2out) {
    __shared__ ushort Elds[32 * E2STR];
    __shared__ ushort Hlds[32 * E2STR];
    __shared__ int nbl[4][KNN];
    int tid = threadIdx.x;
    int P0 = blockIdx.x * 4;

    {   // fused selection: one wave per point
        int lane = tid & 63, wave = tid >> 6;
        u64 best[KNN];
        wave_sel8(d2 + (size_t)(P0 + wave) * NP, lane, best);
        if (lane < KNN) nbl[wave][lane] = (int)(best[lane] & 0xffffffffu);
    }
    __syncthreads();

    {
        int e = tid >> 3, seg = tid & 7;
        int bi = P0 + (e >> 3), k = e & 7;
        int b = bi / NP;
        int nb = nbl[e >> 3][k];
        const float* xi = x1 + (size_t)bi * 32;
        const float* xj = x1 + ((size_t)b * NP + nb) * 32;
        int c0 = seg * 8;
        #pragma unroll
        for (int c = c0; c < c0 + 8; c += 4) {
            float4 v;
            if (c < 32) {
                v = *(const float4*)(xi + c);
            } else {
                float4 a = *(const float4*)(xi + c - 32);
                float4 q = *(const float4*)(xj + c - 32);
                v = make_float4(q.x - a.x, q.y - a.y, q.z - a.z, q.w - a.w);
            }
            uint lo = (uint)f2b(v.x) | ((uint)f2b(v.y) << 16);
            uint hi = (uint)f2b(v.z) | ((uint)f2b(v.w) << 16);
            *(uint2*)(&Elds[e * E2STR + c]) = make_uint2(lo, hi);
        }
    }
    __syncthreads();

    int lane = tid & 63, wave = tid >> 6;
    int n16 = lane & 15, quad = lane >> 4;

    {
        int nc = wave * 16;
        f32x4 acc[2];
        float bv = b1f[nc + n16];
        acc[0] = (f32x4){bv, bv, bv, bv};
        acc[1] = acc[0];
        #pragma unroll
        for (int k8 = 0; k8 < 2; ++k8) {
            int ko = k8 * 32 + quad * 8;
            short8 a0 = *(const short8*)(&Elds[(n16) * E2STR + ko]);
            short8 a1 = *(const short8*)(&Elds[(16 + n16) * E2STR + ko]);
            short8 bfr = *(const short8*)(&w1t[(size_t)(nc + n16) * 64 + ko]);
            acc[0] = __builtin_amdgcn_mfma_f32_16x16x32_bf16(a0, bfr, acc[0], 0, 0, 0);
            acc[1] = __builtin_amdgcn_mfma_f32_16x16x32_bf16(a1, bfr, acc[1], 0, 0, 0);
        }
        #pragma unroll
        for (int mt = 0; mt < 2; ++mt) {
            int col = nc + n16;
            #pragma unroll
            for (int r = 0; r < 4; ++r) {
                int row = mt * 16 + quad * 4 + r;
                Hlds[row * E2STR + col] = f2b(fmaxf(acc[mt][r], 0.f));
            }
        }
    }
    __syncthreads();

    {
        int nc2 = wave * 32;
        f32x4 acc[2][2];
        #pragma unroll
        for (int mt = 0; mt < 2; ++mt)
            #pragma unroll
            for (int nt = 0; nt < 2; ++nt) acc[mt][nt] = (f32x4){0.f, 0.f, 0.f, 0.f};
        #pragma unroll
        for (int k8 = 0; k8 < 2; ++k8) {
            int ko = k8 * 32 + quad * 8;
            short8 a0 = *(const short8*)(&Hlds[(n16) * E2STR + ko]);
            short8 a1 = *(const short8*)(&Hlds[(16 + n16) * E2STR + ko]);
            #pragma unroll
            for (int nt = 0; nt < 2; ++nt) {
                short8 bfr = *(const short8*)(&w2t[(size_t)(nc2 + nt * 16 + n16) * 64 + ko]);
                acc[0][nt] = __builtin_amdgcn_mfma_f32_16x16x32_bf16(a0, bfr, acc[0][nt], 0, 0, 0);
                acc[1][nt] = __builtin_amdgcn_mfma_f32_16x16x32_bf16(a1, bfr, acc[1][nt], 0, 0, 0);
            }
        }
        #pragma unroll
        for (int mt = 0; mt < 2; ++mt)
            #pragma unroll
            for (int nt = 0; nt < 2; ++nt) {
                f32x4 a = acc[mt][nt];
                float v = fmaxf(fmaxf(a[0], a[1]), fmaxf(a[2], a[3]));
                float o = fmaxf(v, __shfl_xor(v, 16, 64));
                int col = nc2 + nt * 16 + n16;
                if (quad == 0)
                    x2out[(size_t)(P0 + mt * 2) * 128 + col] = o + b2f[col];
                else if (quad == 2)
                    x2out[(size_t)(P0 + mt * 2 + 1) * 128 + col] = o + b2f[col];
            }
    }
}

// ---------------- R26: EdgeConv-3 via bf16 MFMA, with FUSED top-8 select ----------------
#define ESTR 264   // LDS row stride (bf16 elems)
__global__ __launch_bounds__(256) void ec3_mfma_kernel(
        const float* __restrict__ x2, const float* __restrict__ d2,
        const ushort* __restrict__ w1t, const ushort* __restrict__ w2t,
        const float* __restrict__ b1f, const float* __restrict__ b2f,
        float* __restrict__ x3) {
    __shared__ ushort Elds[32 * ESTR];
    __shared__ ushort Hlds[32 * ESTR];
    __shared__ int nbl[4][KNN];
    int tid = threadIdx.x;
    int P0 = blockIdx.x * 4;

    {   // fused selection: one wave per point
        int lane = tid & 63, wave = tid >> 6;
        u64 best[KNN];
        wave_sel8(d2 + (size_t)(P0 + wave) * NP, lane, best);
        if (lane < KNN) nbl[wave][lane] = (int)(best[lane] & 0xffffffffu);
    }
    __syncthreads();

    {
        int e = tid >> 3, seg = tid & 7;
        int bi = P0 + (e >> 3), k = e & 7;
        int b = bi / NP;
        int nb = nbl[e >> 3][k];
        const float* xi = x2 + (size_t)bi * 128;
        const float* xj = x2 + ((size_t)b * NP + nb) * 128;
        int c0 = seg * 16;
        #pragma unroll
        for (int c = c0; c < c0 + 16; c += 4) {
            float4 a = *(const float4*)(xi + c);
            float4 q = *(const float4*)(xj + c);
            uint lo = (uint)f2b(a.x) | ((uint)f2b(a.y) << 16);
            uint hi = (uint)f2b(a.z) | ((uint)f2b(a.w) << 16);
            *(uint2*)(&Elds[e * ESTR + c]) = make_uint2(lo, hi);
            lo = (uint)f2b(q.x - a.x) | ((uint)f2b(q.y - a.y) << 16);
            hi = (uint)f2b(q.z - a.z) | ((uint)f2b(q.w - a.w) << 16);
            *(uint2*)(&Elds[e * ESTR + 128 + c]) = make_uint2(lo, hi);
        }
    }
    __syncthreads();

    int lane = tid & 63, wave = tid >> 6;
    int n16 = lane & 15, quad = lane >> 4;

    {
        int nc = wave * 64;
        f32x4 acc1[2][4];
        #pragma unroll
        for (int mt = 0; mt < 2; ++mt)
            #pragma unroll
            for (int nt = 0; nt < 4; ++nt) {
                float bv = b1f[nc + nt * 16 + n16];
                acc1[mt][nt] = (f32x4){bv, bv, bv, bv};
            }
        #pragma unroll
        for (int k8 = 0; k8 < 8; ++k8) {
            int ko = k8 * 32 + quad * 8;
            short8 a0 = *(const short8*)(&Elds[(n16) * ESTR + ko]);
            short8 a1 = *(const short8*)(&Elds[(16 + n16) * ESTR + ko]);
            #pragma unroll
            for (int nt = 0; nt < 4; ++nt) {
                short8 bfr = *(const short8*)(&w1t[(size_t)(nc + nt * 16 + n16) * 256 + ko]);
                acc1[0][nt] = __builtin_amdgcn_mfma_f32_16x16x32_bf16(a0, bfr, acc1[0][nt], 0, 0, 0);
                acc1[1][nt] = __builtin_amdgcn_mfma_f32_16x16x32_bf16(a1, bfr, acc1[1][nt], 0, 0, 0);
            }
        }
        #pragma unroll
        for (int mt = 0; mt < 2; ++mt)
            #pragma unroll
            for (int nt = 0; nt < 4; ++nt) {
                int col = nc + nt * 16 + n16;
                #pragma unroll
                for (int r = 0; r < 4; ++r) {
                    int row = mt * 16 + quad * 4 + r;
                    Hlds[row * ESTR + col] = f2b(fmaxf(acc1[mt][nt][r], 0.f));
                }
            }
    }
    __syncthreads();

    {
        int nc2 = wave * 128;
        f32x4 acc2[2][8];
        #pragma unroll
        for (int mt = 0; mt < 2; ++mt)
            #pragma unroll
            for (int nt = 0; nt < 8; ++nt) acc2[mt][nt] = (f32x4){0.f, 0.f, 0.f, 0.f};
        #pragma unroll
        for (int k8 = 0; k8 < 8; ++k8) {
            int ko = k8 * 32 + quad * 8;
            short8 a0 = *(const short8*)(&Hlds[(n16) * ESTR + ko]);
            short8 a1 = *(const short8*)(&Hlds[(16 + n16) * ESTR + ko]);
            #pragma unroll
            for (int nt = 0; nt < 8; ++nt) {
                short8 bfr = *(const short8*)(&w2t[(size_t)(nc2 + nt * 16 + n16) * 256 + ko]);
                acc2[0][nt] = __builtin_amdgcn_mfma_f32_16x16x32_bf16(a0, bfr, acc2[0][nt], 0, 0, 0);
                acc2[1][nt] = __builtin_amdgcn_mfma_f32_16x16x32_bf16(a1, bfr, acc2[1][nt], 0, 0, 0);
            }
        }
        #pragma unroll
        for (int mt = 0; mt < 2; ++mt)
            #pragma unroll
            for (int nt = 0; nt < 8; ++nt) {
                f32x4 a = acc2[mt][nt];
                float v = fmaxf(fmaxf(a[0], a[1]), fmaxf(a[2], a[3]));
                float o = fmaxf(v, __shfl_xor(v, 16, 64));
                int col = nc2 + nt * 16 + n16;
                if (quad == 0)
                    x3[(size_t)(P0 + mt * 2) * 512 + col] = o + b2f[col];
                else if (quad == 2)
                    x3[(size_t)(P0 + mt * 2 + 1) * 512 + col] = o + b2f[col];
            }
    }
}

// ---------------- shared MLP + hij via bf16 MFMA, fully fused ----------------
#define XSTR 680   // 672+8 bf16
#define SSTR 136   // 128+8
__global__ __launch_bounds__(256) void sm_mfma_kernel(
        const float* __restrict__ x1, const float* __restrict__ x2,
        const float* __restrict__ x3,
        const ushort* __restrict__ w1t, const ushort* __restrict__ w2t,
        const ushort* __restrict__ ecw1t,
        const float* __restrict__ b1f, const float* __restrict__ b2f,
        float* __restrict__ sf, float* __restrict__ hi, float* __restrict__ hj) {
    __shared__ ushort Xlds[32 * XSTR];
    __shared__ ushort Hlds[32 * ESTR];
    __shared__ ushort Slds[32 * SSTR];
    int tid = threadIdx.x;
    int P0 = blockIdx.x * 32;

    {
        int row = tid >> 3, cseg = tid & 7;
        int p = P0 + row;
        bool ok = p < NB * NP;
        #pragma unroll
        for (int k = 0; k < 21; ++k) {
            int c = cseg * 4 + k * 32;
            float4 v = make_float4(0.f, 0.f, 0.f, 0.f);
            if (ok) {
                if (c < 32) v = *(const float4*)(x1 + (size_t)p * 32 + c);
                else if (c < 160) v = *(const float4*)(x2 + (size_t)p * 128 + (c - 32));
                else v = *(const float4*)(x3 + (size_t)p * 512 + (c - 160));
            }
            uint lo = (uint)f2b(v.x) | ((uint)f2b(v.y) << 16);
            uint hv = (uint)f2b(v.z) | ((uint)f2b(v.w) << 16);
            *(uint2*)(&Xlds[row * XSTR + c]) = make_uint2(lo, hv);
        }
    }
    __syncthreads();

    int lane = tid & 63, wave = tid >> 6;
    int n16 = lane & 15, quad = lane >> 4;

    {
        int nc = wave * 64;
        f32x4 acc[2][4];
        #pragma unroll
        for (int mt = 0; mt < 2; ++mt)
            #pragma unroll
            for (int nt = 0; nt < 4; ++nt) {
                float bv = b1f[nc + nt * 16 + n16];
                acc[mt][nt] = (f32x4){bv, bv, bv, bv};
            }
        #pragma unroll
        for (int k8 = 0; k8 < 21; ++k8) {
            int ko = k8 * 32 + quad * 8;
            short8 a0 = *(const short8*)(&Xlds[(n16) * XSTR + ko]);
            short8 a1 = *(const short8*)(&Xlds[(16 + n16) * XSTR + ko]);
            #pragma unroll
            for (int nt = 0; nt < 4; ++nt) {
                short8 bfr = *(const short8*)(&w1t[(size_t)(nc + nt * 16 + n16) * 672 + ko]);
                acc[0][nt] = __builtin_amdgcn_mfma_f32_16x16x32_bf16(a0, bfr, acc[0][nt], 0, 0, 0);
                acc[1][nt] = __builtin_amdgcn_mfma_f32_16x16x32_bf16(a1, bfr, acc[1][nt], 0, 0, 0);
            }
        }
        #pragma unroll
        for (int mt = 0; mt < 2; ++mt)
            #pragma unroll
            for (int nt = 0; nt < 4; ++nt) {
                int col = nc + nt * 16 + n16;
                #pragma unroll
                for (int r = 0; r < 4; ++r) {
                    int row = mt * 16 + quad * 4 + r;
                    Hlds[row * ESTR + col] = f2b(fmaxf(acc[mt][nt][r], 0.f));
                }
            }
    }
    __syncthreads();

    {
        int nc = wave * 32;
        f32x4 acc[2][2];
        #pragma unroll
        for (int mt = 0; mt < 2; ++mt)
            #pragma unroll
            for (int nt = 0; nt < 2; ++nt) {
                float bv = b2f[nc + nt * 16 + n16];
                acc[mt][nt] = (f32x4){bv, bv, bv, bv};
            }
        #pragma unroll
        for (int k8 = 0; k8 < 8; ++k8) {
            int ko = k8 * 32 + quad * 8;
            short8 a0 = *(const short8*)(&Hlds[(n16) * ESTR + ko]);
            short8 a1 = *(const short8*)(&Hlds[(16 + n16) * ESTR + ko]);
            #pragma unroll
            for (int nt = 0; nt < 2; ++nt) {
                short8 bfr = *(const short8*)(&w2t[(size_t)(nc + nt * 16 + n16) * 256 + ko]);
                acc[0][nt] = __builtin_amdgcn_mfma_f32_16x16x32_bf16(a0, bfr, acc[0][nt], 0, 0, 0);
                acc[1][nt] = __builtin_amdgcn_mfma_f32_16x16x32_bf16(a1, bfr, acc[1][nt], 0, 0, 0);
            }
        }
        #pragma unroll
        for (int mt = 0; mt < 2; ++mt)
            #pragma unroll
            for (int nt = 0; nt < 2; ++nt) {
                int col = nc + nt * 16 + n16;
                #pragma unroll
                for (int r = 0; r < 4; ++r) {
                    int row = mt * 16 + quad * 4 + r;
                    int p = P0 + row;
                    float v = acc[mt][nt][r];
                    if (p < NB * NP) sf[(size_t)p * 128 + col] = v;
                    Slds[row * SSTR + col] = f2b(v);
                }
            }
    }
    __syncthreads();

    {
        int nc = wave * 64;
        f32x4 acc[2][4];
        #pragma unroll
        for (int mt = 0; mt < 2; ++mt)
            #pragma unroll
            for (int nt = 0; nt < 4; ++nt) acc[mt][nt] = (f32x4){0.f, 0.f, 0.f, 0.f};
        #pragma unroll
        for (int k8 = 0; k8 < 4; ++k8) {
            int ko = k8 * 32 + quad * 8;
            short8 a0 = *(const short8*)(&Slds[(n16) * SSTR + ko]);
            short8 a1 = *(const short8*)(&Slds[(16 + n16) * SSTR + ko]);
            #pragma unroll
            for (int nt = 0; nt < 4; ++nt) {
                short8 bfr = *(const short8*)(&ecw1t[(size_t)(nc + nt * 16 + n16) * 128 + ko]);
                acc[0][nt] = __builtin_amdgcn_mfma_f32_16x16x32_bf16(a0, bfr, acc[0][nt], 0, 0, 0);
                acc[1][nt] = __builtin_amdgcn_mfma_f32_16x16x32_bf16(a1, bfr, acc[1][nt], 0, 0, 0);
            }
        }
        #pragma unroll
        for (int mt = 0; mt < 2; ++mt)
            #pragma unroll
            for (int nt = 0; nt < 4; ++nt) {
                int colp = nc + nt * 16 + n16;
                float* dst = (colp < 128) ? hi : hj;
                int col = colp & 127;
                #pragma unroll
                for (int r = 0; r < 4; ++r) {
                    int row = mt * 16 + quad * 4 + r;
                    int p = P0 + row;
                    if (p < NB * NP) dst[(size_t)p * 128 + col] = acc[mt][nt][r];
                }
            }
    }
}

// ---------------- global max pool stage 1 (restored R28: 50-block parallelism) ----------
__global__ void gmax1_kernel(const float* __restrict__ sf, float* __restrict__ part) {
    int m = blockIdx.x;
    int b = m / 25, ch = m % 25, o = threadIdx.x;
    float v = -INFINITY;
    int n0 = ch * 40;
    for (int n = n0; n < n0 + 40; ++n)
        v = fmaxf(v, sf[((size_t)b * NP + n) * 128 + o]);
    part[(size_t)m * 128 + o] = v;
}

// ---------------- fused final max + hg = g @ W[256:384] + b1 ----------------
__global__ void gfin_kernel(const float* __restrict__ part, const float* __restrict__ w1,
                            const float* __restrict__ b1, float* __restrict__ hg) {
    int b = blockIdx.x, o = threadIdx.x;   // 128 threads
    __shared__ float gs[128];
    float v = -INFINITY;
    for (int ch = 0; ch < 25; ++ch)
        v = fmaxf(v, part[((size_t)b * 25 + ch) * 128 + o]);
    gs[o] = v;
    __syncthreads();
    float acc = b1[o];
    for (int c = 0; c < 128; ++c) acc += gs[c] * w1[(256 + c) * 128 + o];
    hg[b * 128 + o] = acc;
}

// ---------------- pairwise scorer: R17 structure (best measured total) ----------------
#define PLD(o4, A_, H0_, H1_, W_)                                              \
    {                                                                          \
        W_  = *(const float4*)(&w2s[(o4) * 4]);                                \
        H0_ = *(const float4*)(&hjt[tj][(o4) * 4]);                            \
        H1_ = *(const float4*)(&hjt[tj + 32][(o4) * 4]);                       \
        _Pragma("unroll")                                                      \
        for (int r = 0; r < 4; ++r)                                            \
            A_[r] = *(const float4*)(&hit[ti3 * 4 + r][(o4) * 4]);             \
    }
#define PCOMP(A_, H0_, H1_, W_)                                                \
    {                                                                          \
        _Pragma("unroll")                                                      \
        for (int r = 0; r < 4; ++r) {                                          \
            float4 a = A_[r];                                                  \
            acc[r][0] += fmaxf(a.x + H0_.x, 0.f) * W_.x                        \
                       + fmaxf(a.y + H0_.y, 0.f) * W_.y                        \
                       + fmaxf(a.z + H0_.z, 0.f) * W_.z                        \
                       + fmaxf(a.w + H0_.w, 0.f) * W_.w;                       \
            acc[r][1] += fmaxf(a.x + H1_.x, 0.f) * W_.x                        \
                       + fmaxf(a.y + H1_.y, 0.f) * W_.y                        \
                       + fmaxf(a.z + H1_.z, 0.f) * W_.z                        \
                       + fmaxf(a.w + H1_.w, 0.f) * W_.w;                       \
        }                                                                      \
    }

__global__ __launch_bounds__(256) void pair_kernel(
        const float* __restrict__ hi, const float* __restrict__ hj,
        const float* __restrict__ hg,
        const float* __restrict__ w2, const float* __restrict__ b2,
        void* __restrict__ out, const int* __restrict__ flag) {
    int j0 = blockIdx.x * 64, i0 = blockIdx.y * 32, b = blockIdx.z;
    if (j0 + 63 <= i0) return;    // no j > i possible in this tile
    __shared__ float hit[32][132];
    __shared__ float hjt[64][132];
    __shared__ __align__(16) float w2s[128];
    int tid = threadIdx.x;
    if (tid < 128) w2s[tid] = w2[tid];
    int c4 = tid & 31;   // fixed per thread (stride 256 = 8 rows)
    float4 hgv = *(const float4*)(hg + b * 128 + c4 * 4);
    for (int t = tid; t < 96 * 32; t += 256) {
        int row = t >> 5;
        if (row < 32) {
            int i = i0 + row;
            float4 v = make_float4(0.f, 0.f, 0.f, 0.f);
            if (i < NP) v = *(const float4*)(hi + ((size_t)b * NP + i) * 128 + c4 * 4);
            *(float4*)(&hit[row][c4 * 4]) = v;
        } else {
            int j = j0 + row - 32;
            float4 v = make_float4(0.f, 0.f, 0.f, 0.f);
            if (j < NP) v = *(const float4*)(hj + ((size_t)b * NP + j) * 128 + c4 * 4);
            *(float4*)(&hjt[row - 32][c4 * 4]) =
                make_float4(v.x + hgv.x, v.y + hgv.y, v.z + hgv.z, v.w + hgv.w);
        }
    }
    __syncthreads();

    int tj = tid & 31;       // 32 j-lanes (rows tj / tj+32 of hjt)
    int ti3 = tid >> 5;      // 8 i-groups of 4 rows
    float acc[4][2] = {{0.f, 0.f}, {0.f, 0.f}, {0.f, 0.f}, {0.f, 0.f}};

    // 2-stage software pipeline: o4+1's 7 LDS loads issued before o4's compute retires
    float4 A0[4], H00, H01, W0;
    float4 A1[4], H10, H11, W1;
    PLD(0, A0, H00, H01, W0)
    for (int o = 0; o < 32; o += 2) {
        PLD(o + 1, A1, H10, H11, W1)
        PCOMP(A0, H00, H01, W0)
        if (o + 2 < 32) PLD(o + 2, A0, H00, H01, W0)
        PCOMP(A1, H10, H11, W1)
    }

    float bb = b2[0];
    int f = flag[0];
    #pragma unroll
    for (int r = 0; r < 4; ++r) {
        int i = i0 + ti3 * 4 + r;
        #pragma unroll
        for (int jj = 0; jj < 2; ++jj) {
            int j = j0 + tj + jj * 32;
            if (i < j && j < NP) {
                size_t p = (size_t)i * (NP - 1) - (size_t)i * (i - 1) / 2 + (j - i - 1);
                float mo = acc[r][jj] + bb;
                float pr = 1.f / (1.f + expf(-mo));
                size_t idx0 = (size_t)b * PPAIR + p;
                size_t idx1 = (size_t)NB * PPAIR + idx0;
                if (f) {
                    ((float*)out)[idx0] = pr;
                    ((float*)out)[idx1] = mo;
                } else {
                    ((bf16*)out)[idx0] = __float2bfloat16(pr);
                    ((bf16*)out)[idx1] = __float2bfloat16(mo);
                }
            }
        }
    }
}

extern "C" void kernel_launch(void* const* d_in, const int* in_sizes, int n_in,
                              void* d_out, int out_size, void* d_ws, size_t ws_size,
                              hipStream_t stream) {
    float* ws = (float*)d_ws;
    float* posf = ws + OFF_POS;
    float* x1   = ws + OFF_X1;
    float* x2   = ws + OFF_X2;
    float* x3   = ws + OFF_X3;
    float* sf   = ws + OFF_SF;
    float* hi   = ws + OFF_HI;
    float* hj   = ws + OFF_HJ;
    float* hgb  = ws + OFF_HG;
    int*   flag = (int*)(ws + OFF_FLAG);
    float* gp   = ws + OFF_GP;
    float* d2m  = ws + OFF_D2;
    ushort* w1t = (ushort*)(ws + OFF_W1T);
    ushort* w2t = (ushort*)(ws + OFF_W2T);
    ushort* smw1t = (ushort*)(ws + OFF_SMW1T);
    ushort* smw2t = (ushort*)(ws + OFF_SMW2T);
    ushort* ecw1t = (ushort*)(ws + OFF_ECW1T);
    ushort* e2w1t = (ushort*)(ws + OFF_E2W1T);
    ushort* e2w2t = (ushort*)(ws + OFF_E2W2T);

    // 1) detect input dtype (bf16 vs f32) on-device
    detect_kernel<<<1, 256, 0, stream>>>(d_in[0], flag);

    // 2) convert all inputs to f32 + build all transposed bf16 weights
    //    (flattened 1-D grid: 3591 working blocks)
    InPtrs ip;
    for (int i = 0; i < 21; ++i) ip.p[i] = d_in[i];
    cvt_all_kernel<<<3591, 256, 0, stream>>>(ip, ws, flag, w1t, w2t, smw1t, smw2t,
                                             ecw1t, e2w1t, e2w2t);

    dim3 kgrid_f(NP / 8, NB);                      // fused knn<3>+ec1
    dim3 dgrid(32, 16, 2);                          // dist tiles: 32x64, 2 batches

    // 3) EdgeConv 1 (C=3 -> 32): fused kNN + wave-per-point EdgeConv
    knn_ec1_kernel<<<kgrid_f, 256, 0, stream>>>(
        posf, ws + OFF_C1W1, ws + OFF_C1B1, ws + OFF_C1W2, ws + OFF_C1B2, x1);

    // 4) EdgeConv 2 (C=32 -> 128): dist matrix + fused select+MFMA
    dist_kernel<32><<<dgrid, 256, 0, stream>>>(x1, d2m);
    ec2_mfma_kernel<<<NB * NP / 4, 256, 0, stream>>>(
        x1, d2m, e2w1t, e2w2t, ws + OFF_C2B1, ws + OFF_C2B2, x2);

    // 5) EdgeConv 3 (C=128 -> 512): dist matrix + fused select+MFMA
    dist_kernel<128><<<dgrid, 256, 0, stream>>>(x2, d2m);
    ec3_mfma_kernel<<<NB * NP / 4, 256, 0, stream>>>(
        x2, d2m, w1t, w2t, ws + OFF_C3B1, ws + OFF_C3B2, x3);

    // 6) shared MLP + hij via MFMA -> sf, hi, hj
    sm_mfma_kernel<<<(NB * NP + 31) / 32, 256, 0, stream>>>(
        x1, x2, x3, smw1t, smw2t, ecw1t, ws + OFF_SMB1, ws + OFF_SMB2, sf, hi, hj);

    // 7) global max pool + hg projection (restored R28: gmax1 50 blk + gfin 2 blk)
    gmax1_kernel<<<NB * 25, 128, 0, stream>>>(sf, gp);
    gfin_kernel<<<NB, 128, 0, stream>>>(gp, ws + OFF_ECW1, ws + OFF_ECB1, hgb);

    // 8) pairwise scorer (R17 structure: 32x64 tiles, f32, 2-stage pipeline)
    dim3 pgrid(16, 32, NB);
    pair_kernel<<<pgrid, 256, 0, stream>>>(hi, hj, hgb, ws + OFF_ECW2, ws + OFF_ECB2,
                                           d_out, flag);
}